// Round 6
// baseline (171.833 us; speedup 1.0000x reference)
//
#include <hip/hip_runtime.h>
#include <hip/hip_bf16.h>

typedef __attribute__((ext_vector_type(8))) short bf16x8;
typedef __attribute__((ext_vector_type(4))) float f32x4;

#define B_   2
#define C_   128
#define D_   6
#define H_   56
#define W_   56
#define N_   12      // B_*D_
#define HW   3136
#define CSTR (D_*HW) // 18816
#define COUT 128
#define OFFP 80      // padded offset-channel stride (72 used)

__device__ __forceinline__ float bf2f(ushort u) {
  return __uint_as_float(((unsigned int)u) << 16);
}
__device__ __forceinline__ ushort f2bf(float f) {  // RNE
  unsigned int x = __float_as_uint(f);
  x += 0x7FFFu + ((x >> 16) & 1u);
  return (ushort)(x >> 16);
}

// ---------------- x (b,c,d,h,w) f32 -> xcl[n][hw][c] bf16 ----------------
__global__ __launch_bounds__(256) void k_transpose(const float* __restrict__ x,
                                                   ushort* __restrict__ xcl) {
  __shared__ float tile[32][57];
  const int h = blockIdx.x, c0 = blockIdx.y * 32, n = blockIdx.z;
  const int b = n / D_, d = n % D_;
  const float* src = x + (((size_t)(b * C_ + c0) * D_ + d) * HW) + h * W_;
  for (int i = threadIdx.x; i < 32 * W_; i += 256) {
    const int c = i / W_, w = i - c * W_;
    tile[c][w] = src[(size_t)c * CSTR + w];
  }
  __syncthreads();
  ushort* dst = xcl + ((size_t)(n * HW + h * W_)) * C_ + c0;
  for (int i = threadIdx.x; i < 32 * W_; i += 256) {
    const int w = i >> 5, c = i & 31;
    dst[(size_t)w * C_ + c] = f2bf(tile[c][w]);
  }
}

// ---- merged weight prep ----
// wd2[((g*36 + ts*4 + q)*32 + co_l)*8 + e] = cw[((g*32+co_l)*32 + q*8 + e)*9 + ts]
// wob2[((tap*16+kq*4+q)*80 + co)*8 + e]   = ow[(co*128 + kq*32+q*8+e)*9 + tap] (co<72)
__global__ void k_wprep(const float* __restrict__ cw, const float* __restrict__ ow,
                        ushort* __restrict__ wd2, ushort* __restrict__ wob2) {
  const int idx = blockIdx.x * 256 + threadIdx.x;  // < 129024
  if (idx < COUT * 288) {
    const int g = idx / 9216;
    const int r = idx - g * 9216;
    const int kb = r >> 8;           // 0..35
    const int co_l = (r >> 3) & 31;
    const int e = r & 7;
    const int ts = kb >> 2;
    const int q = kb & 3;
    wd2[idx] = f2bf(cw[((size_t)(g * 32 + co_l) * 32 + q * 8 + e) * 9 + ts]);
  } else if (idx < COUT * 288 + 144 * OFFP * 8) {
    const int i2 = idx - COUT * 288;
    const int e = i2 & 7;
    const int co = (i2 >> 3) % OFFP;
    const int kb = i2 / (OFFP * 8);   // 0..143
    const int tap = kb >> 4;
    const int r16 = kb & 15;
    const int kq = r16 >> 2;
    const int q = r16 & 3;
    const int c = kq * 32 + q * 8 + e;
    float v = 0.f;
    if (co < 72) v = ow[((size_t)co * C_ + c) * 9 + tap];
    wob2[i2] = f2bf(v);
  }
}

// ---------------- offset conv via MFMA implicit GEMM ----------------
// grid (4, 56, 12), block 320 = 5 waves; wave nt owns N-tile of 16 co; M-tile 16 px
__global__ __launch_bounds__(320) void k_offset_conv(const ushort* __restrict__ xcl,
    const ushort* __restrict__ wob2, const float* __restrict__ ob,
    float* __restrict__ offb2) {
  __shared__ __align__(16) ushort xr[3 * 24 * 128];  // 18432 B, XOR-swizzled
  const int w0 = blockIdx.x * 16;
  const int h = blockIdx.y, n = blockIdx.z;
  const int t = threadIdx.x;
  // stage rows h-1..h+1, slots s=0..17 (w = w0-1+s), zero-padded
  for (int i = t; i < 864; i += 320) {
    const int c16 = i & 15;
    const int sdy = i >> 4;          // 0..53
    const int s = sdy % 18;
    const int dy = sdy / 18;
    const int w = w0 - 1 + s;
    const int rr = h + dy - 1;
    const int c0 = c16 * 8;
    const int db = (((dy * 24 + s) * 128 + c0) * 2) ^ ((s & 7) << 4);
    uint4 v = {0u, 0u, 0u, 0u};
    if ((unsigned)rr < (unsigned)H_ && (unsigned)w < (unsigned)W_)
      v = *(const uint4*)(xcl + ((size_t)(n * HW + rr * W_ + w)) * C_ + c0);
    *(uint4*)((char*)xr + db) = v;
  }
  __syncthreads();
  const int l = t & 63;
  const int nt = t >> 6;             // 0..4
  const int lf = l & 15, q = l >> 4; // q 0..3
  f32x4 acc = {};
#pragma unroll 3
  for (int tap = 0; tap < 9; ++tap) {
    const int dy = tap / 3, kxr = tap - dy * 3;
    const int s = lf + kxr;
#pragma unroll
    for (int kq = 0; kq < 4; ++kq) {
      const int ab = (((dy * 24 + s) * 128 + kq * 32 + q * 8) * 2) ^ ((s & 7) << 4);
      const bf16x8 a = *(const bf16x8*)((const char*)xr + ab);
      const bf16x8 bb = *(const bf16x8*)(wob2 +
          ((size_t)(tap * 16 + kq * 4 + q) * OFFP + nt * 16 + lf) * 8);
      acc = __builtin_amdgcn_mfma_f32_16x16x32_bf16(a, bb, acc, 0, 0, 0);
    }
  }
  const int co = nt * 16 + lf;
  const float bias = (co < 72) ? ob[co] : 0.f;
  float* orow = offb2 + ((size_t)n * HW + h * W_) * OFFP;
#pragma unroll
  for (int r = 0; r < 4; ++r) {
    const int w = w0 + q * 4 + r;
    if (w < W_) orow[(size_t)w * OFFP + co] = acc[r] + bias;
  }
}

// ---------------- deformable conv: setup -> register-direct sample+MFMA ----------------
// grid (196, 12), block 256, 4 waves = 4 groups. LDS 24.4 KB (tables + separate outs).
__global__ __launch_bounds__(256) void k_deform(const ushort* __restrict__ xcl,
    const float* __restrict__ offb2, const ushort* __restrict__ wd2,
    const float* __restrict__ cb, float* __restrict__ out) {
  __shared__ __align__(16) unsigned char sm[14208];
  __shared__ __align__(16) float outs[2560];   // [co][20] padded pixel stride
  ushort* swW = (ushort*)sm;            // [p*148 + (g*9+k)*4], 4736 B
  int* swO = (int*)(sm + 4736);         // [p*148 + (g*9+k)*4], 9472 B

  const int hw0 = blockIdx.x * 16;
  const int n = blockIdx.y;
  const int t = threadIdx.x;

  // ---- setup: one bilinear item per (p,g,k)
  for (int i = t; i < 576; i += 256) {
    const int p = i / 36;
    const int r = i - p * 36;
    const int g = r / 9;
    const int k = r - g * 9;
    const int hw = hw0 + p;
    const int h = hw / 56;
    const int w = hw - h * 56;
    const float2 o2 = *(const float2*)(offb2 + (size_t)(n * HW + hw) * OFFP + g * 18 + 2 * k);
    const int ky = k / 3 - 1;
    const int kx = k - (k / 3) * 3 - 1;
    const float py = (float)(h + ky) + o2.x;
    const float px = (float)(w + kx) + o2.y;
    const float y0f = floorf(py), x0f = floorf(px);
    const float ly = py - y0f, lx = px - x0f;
    const int y0 = (int)y0f, x0 = (int)x0f;
    const int y1 = y0 + 1, x1 = x0 + 1;
    const int yc0 = min(max(y0, 0), H_ - 1), yc1 = min(max(y1, 0), H_ - 1);
    const int xc0 = min(max(x0, 0), W_ - 1), xc1 = min(max(x1, 0), W_ - 1);
    const float my0 = ((unsigned)y0 < (unsigned)H_) ? 1.f : 0.f;
    const float my1 = ((unsigned)y1 < (unsigned)H_) ? 1.f : 0.f;
    const float mx0 = ((unsigned)x0 < (unsigned)W_) ? 1.f : 0.f;
    const float mx1 = ((unsigned)x1 < (unsigned)W_) ? 1.f : 0.f;
    ushort4 wq;
    wq.x = f2bf((1.f - ly) * (1.f - lx) * my0 * mx0);
    wq.y = f2bf((1.f - ly) * lx * my0 * mx1);
    wq.z = f2bf(ly * (1.f - lx) * my1 * mx0);
    wq.w = f2bf(ly * lx * my1 * mx1);
    *(ushort4*)(swW + p * 148 + (g * 9 + k) * 4) = wq;
    int4 oq;
    oq.x = (yc0 * 56 + xc0) * 128;
    oq.y = (yc0 * 56 + xc1) * 128;
    oq.z = (yc1 * 56 + xc0) * 128;
    oq.w = (yc1 * 56 + xc1) * 128;
    *(int4*)(swO + p * 148 + (g * 9 + k) * 4) = oq;
  }
  __syncthreads();

  // ---- fused sample+MFMA: wave = group g; lane (lf,q) samples its own A-fragment
  const int l = t & 63;
  const int g = t >> 6;
  const int lf = l & 15, q = l >> 4;
  const ushort* xb = xcl + (size_t)n * HW * C_ + g * 32 + q * 8;
  const ushort* bb = wd2 + ((size_t)(g * 36 + q) * 32 + lf) * 8;
  const int sbase = lf * 148 + g * 36;
  f32x4 acc0 = {}, acc1 = {};
#pragma unroll 3
  for (int ts = 0; ts < 9; ++ts) {
    const ushort4 wq = *(const ushort4*)(swW + sbase + ts * 4);
    const int4 oq = *(const int4*)(swO + sbase + ts * 4);
    const uint4 c00 = *(const uint4*)(xb + oq.x);
    const uint4 c01 = *(const uint4*)(xb + oq.y);
    const uint4 c10 = *(const uint4*)(xb + oq.z);
    const uint4 c11 = *(const uint4*)(xb + oq.w);
    const float w00 = bf2f(wq.x), w01 = bf2f(wq.y);
    const float w10 = bf2f(wq.z), w11 = bf2f(wq.w);
    bf16x8 av;
#pragma unroll
    for (int j = 0; j < 4; ++j) {
      const unsigned int u00 = ((const unsigned int*)&c00)[j];
      const unsigned int u01 = ((const unsigned int*)&c01)[j];
      const unsigned int u10 = ((const unsigned int*)&c10)[j];
      const unsigned int u11 = ((const unsigned int*)&c11)[j];
      const float lo = fmaf(w00, __uint_as_float(u00 << 16),
                       fmaf(w01, __uint_as_float(u01 << 16),
                       fmaf(w10, __uint_as_float(u10 << 16),
                            w11 * __uint_as_float(u11 << 16))));
      const float hi = fmaf(w00, __uint_as_float(u00 & 0xFFFF0000u),
                       fmaf(w01, __uint_as_float(u01 & 0xFFFF0000u),
                       fmaf(w10, __uint_as_float(u10 & 0xFFFF0000u),
                            w11 * __uint_as_float(u11 & 0xFFFF0000u))));
      av[2 * j]     = (short)f2bf(lo);
      av[2 * j + 1] = (short)f2bf(hi);
    }
    const bf16x8 b0 = *(const bf16x8*)(bb + (size_t)ts * 4 * 32 * 8);
    const bf16x8 b1 = *(const bf16x8*)(bb + (size_t)ts * 4 * 32 * 8 + 16 * 8);
    acc0 = __builtin_amdgcn_mfma_f32_16x16x32_bf16(av, b0, acc0, 0, 0, 0);
    acc1 = __builtin_amdgcn_mfma_f32_16x16x32_bf16(av, b1, acc1, 0, 0, 0);
  }
  // outs is a separate buffer — no barrier needed before writing it
#pragma unroll
  for (int r = 0; r < 4; ++r) {
    outs[(g * 32 + lf) * 20 + q * 4 + r] = acc0[r] + cb[g * 32 + lf];
    outs[(g * 32 + 16 + lf) * 20 + q * 4 + r] = acc1[r] + cb[g * 32 + 16 + lf];
  }
  __syncthreads();
  {
    const int co = t & 127;
    const int hf = t >> 7;
    const float4 v0 = *(const float4*)(outs + co * 20 + hf * 8);
    const float4 v1 = *(const float4*)(outs + co * 20 + hf * 8 + 4);
    const int b = n / D_, d = n - b * D_;
    float* dst = out + ((size_t)(b * COUT + co) * D_ + d) * HW + hw0 + hf * 8;
    *(float4*)dst = v0;
    *(float4*)(dst + 4) = v1;
  }
}

// ---------------- instance norm over (D,H,W) + exact GELU, in-place ----------------
__global__ __launch_bounds__(512) void k_norm_gelu(float* __restrict__ io) {
  const int M = D_ * HW;       // 18816
  const int M4 = M / 4;        // 4704
  float4* p = (float4*)(io + (size_t)blockIdx.x * M);
  float s = 0.f, s2 = 0.f;
  for (int i = threadIdx.x; i < M4; i += 512) {
    const float4 v = p[i];
    s += v.x + v.y + v.z + v.w;
    s2 = fmaf(v.x, v.x, fmaf(v.y, v.y, fmaf(v.z, v.z, fmaf(v.w, v.w, s2))));
  }
#pragma unroll
  for (int off = 32; off > 0; off >>= 1) {
    s += __shfl_down(s, off, 64);
    s2 += __shfl_down(s2, off, 64);
  }
  __shared__ float rs[8], rs2[8];
  __shared__ float smu, srstd;
  const int wid = threadIdx.x >> 6, lane = threadIdx.x & 63;
  if (lane == 0) { rs[wid] = s; rs2[wid] = s2; }
  __syncthreads();
  if (threadIdx.x == 0) {
    float ts = 0.f, t2 = 0.f;
#pragma unroll
    for (int i = 0; i < 8; ++i) { ts += rs[i]; t2 += rs2[i]; }
    const float mu = ts / (float)M;
    const float var = t2 / (float)M - mu * mu;
    smu = mu;
    srstd = rsqrtf(var + 1e-5f);
  }
  __syncthreads();
  const float mu = smu, rstd = srstd;
  for (int i = threadIdx.x; i < M4; i += 512) {
    float4 v = p[i];
    v.x = (v.x - mu) * rstd; v.y = (v.y - mu) * rstd;
    v.z = (v.z - mu) * rstd; v.w = (v.w - mu) * rstd;
    v.x = 0.5f * v.x * (1.f + erff(v.x * 0.70710678118654752f));
    v.y = 0.5f * v.y * (1.f + erff(v.y * 0.70710678118654752f));
    v.z = 0.5f * v.z * (1.f + erff(v.z * 0.70710678118654752f));
    v.w = 0.5f * v.w * (1.f + erff(v.w * 0.70710678118654752f));
    p[i] = v;
  }
}

extern "C" void kernel_launch(void* const* d_in, const int* in_sizes, int n_in,
                              void* d_out, int out_size, void* d_ws, size_t ws_size,
                              hipStream_t stream) {
  const float* x  = (const float*)d_in[0];
  const float* ow = (const float*)d_in[1];
  const float* ob = (const float*)d_in[2];
  const float* cw = (const float*)d_in[3];
  const float* cb = (const float*)d_in[4];
  float* outp = (float*)d_out;

  char* wsb = (char*)d_ws;
  ushort* xcl   = (ushort*)wsb;                       // 9,633,792 B
  float*  offb2 = (float*)(wsb + 9633792);            // 12,042,240 B
  ushort* wd2   = (ushort*)(wsb + 21676032);          // 73,728 B
  ushort* wob2  = (ushort*)(wsb + 21749760);          // 184,320 B

  k_wprep<<<dim3(504), 256, 0, stream>>>(cw, ow, wd2, wob2);
  k_transpose<<<dim3(H_, 4, N_), 256, 0, stream>>>(x, xcl);
  k_offset_conv<<<dim3(4, H_, N_), 320, 0, stream>>>(xcl, wob2, ob, offb2);
  k_deform<<<dim3(196, N_), 256, 0, stream>>>(xcl, offb2, wd2, cb, outp);
  k_norm_gelu<<<dim3(B_ * COUT), 512, 0, stream>>>(outp);
}

// Round 7
// 164.779 us; speedup vs baseline: 1.0428x; 1.0428x over previous
//
#include <hip/hip_runtime.h>
#include <hip/hip_bf16.h>

typedef __attribute__((ext_vector_type(8))) short bf16x8;
typedef __attribute__((ext_vector_type(4))) float f32x4;

#define B_   2
#define C_   128
#define D_   6
#define H_   56
#define W_   56
#define N_   12      // B_*D_
#define HW   3136
#define CSTR (D_*HW) // 18816
#define COUT 128
#define OFFP 80      // padded offset-channel stride (72 used)

__device__ __forceinline__ float bf2f(ushort u) {
  return __uint_as_float(((unsigned int)u) << 16);
}
__device__ __forceinline__ ushort f2bf(float f) {  // RNE
  unsigned int x = __float_as_uint(f);
  x += 0x7FFFu + ((x >> 16) & 1u);
  return (ushort)(x >> 16);
}

// ---------------- x (b,c,d,h,w) f32 -> xcl[n][hw][c] bf16 ----------------
__global__ __launch_bounds__(256) void k_transpose(const float* __restrict__ x,
                                                   ushort* __restrict__ xcl) {
  __shared__ float tile[32][57];
  const int h = blockIdx.x, c0 = blockIdx.y * 32, n = blockIdx.z;
  const int b = n / D_, d = n % D_;
  const float* src = x + (((size_t)(b * C_ + c0) * D_ + d) * HW) + h * W_;
  for (int i = threadIdx.x; i < 32 * W_; i += 256) {
    const int c = i / W_, w = i - c * W_;
    tile[c][w] = src[(size_t)c * CSTR + w];
  }
  __syncthreads();
  ushort* dst = xcl + ((size_t)(n * HW + h * W_)) * C_ + c0;
  for (int i = threadIdx.x; i < 32 * W_; i += 256) {
    const int w = i >> 5, c = i & 31;
    dst[(size_t)w * C_ + c] = f2bf(tile[c][w]);
  }
}

// ---- merged weight prep ----
// wd2[((g*36 + ts*4 + q)*32 + co_l)*8 + e] = cw[((g*32+co_l)*32 + q*8 + e)*9 + ts]
// wob2[((tap*16+kq*4+q)*80 + co)*8 + e]   = ow[(co*128 + kq*32+q*8+e)*9 + tap] (co<72)
__global__ void k_wprep(const float* __restrict__ cw, const float* __restrict__ ow,
                        ushort* __restrict__ wd2, ushort* __restrict__ wob2) {
  const int idx = blockIdx.x * 256 + threadIdx.x;  // < 129024
  if (idx < COUT * 288) {
    const int g = idx / 9216;
    const int r = idx - g * 9216;
    const int kb = r >> 8;           // 0..35
    const int co_l = (r >> 3) & 31;
    const int e = r & 7;
    const int ts = kb >> 2;
    const int q = kb & 3;
    wd2[idx] = f2bf(cw[((size_t)(g * 32 + co_l) * 32 + q * 8 + e) * 9 + ts]);
  } else if (idx < COUT * 288 + 144 * OFFP * 8) {
    const int i2 = idx - COUT * 288;
    const int e = i2 & 7;
    const int co = (i2 >> 3) % OFFP;
    const int kb = i2 / (OFFP * 8);   // 0..143
    const int tap = kb >> 4;
    const int r16 = kb & 15;
    const int kq = r16 >> 2;
    const int q = r16 & 3;
    const int c = kq * 32 + q * 8 + e;
    float v = 0.f;
    if (co < 72) v = ow[((size_t)co * C_ + c) * 9 + tap];
    wob2[i2] = f2bf(v);
  }
}

// ---------------- offset conv via MFMA implicit GEMM ----------------
// grid (4, 56, 12), block 320 = 5 waves; wave nt owns N-tile of 16 co; M-tile 16 px
__global__ __launch_bounds__(320) void k_offset_conv(const ushort* __restrict__ xcl,
    const ushort* __restrict__ wob2, const float* __restrict__ ob,
    float* __restrict__ offb2) {
  __shared__ __align__(16) ushort xr[3 * 24 * 128];  // 18432 B, XOR-swizzled
  const int w0 = blockIdx.x * 16;
  const int h = blockIdx.y, n = blockIdx.z;
  const int t = threadIdx.x;
  // stage rows h-1..h+1, slots s=0..17 (w = w0-1+s), zero-padded
  for (int i = t; i < 864; i += 320) {
    const int c16 = i & 15;
    const int sdy = i >> 4;          // 0..53
    const int s = sdy % 18;
    const int dy = sdy / 18;
    const int w = w0 - 1 + s;
    const int rr = h + dy - 1;
    const int c0 = c16 * 8;
    const int db = (((dy * 24 + s) * 128 + c0) * 2) ^ ((s & 7) << 4);
    uint4 v = {0u, 0u, 0u, 0u};
    if ((unsigned)rr < (unsigned)H_ && (unsigned)w < (unsigned)W_)
      v = *(const uint4*)(xcl + ((size_t)(n * HW + rr * W_ + w)) * C_ + c0);
    *(uint4*)((char*)xr + db) = v;
  }
  __syncthreads();
  const int l = t & 63;
  const int nt = t >> 6;             // 0..4
  const int lf = l & 15, q = l >> 4; // q 0..3
  const ushort* wbase = wob2 + ((size_t)q * OFFP + nt * 16 + lf) * 8;
  f32x4 acc = {};
  // B-frag prefetch pipeline (distance 1 tap = 4 frags ahead)
  bf16x8 Bf[9][4];
#pragma unroll
  for (int kq = 0; kq < 4; ++kq)
    Bf[0][kq] = *(const bf16x8*)(wbase + (size_t)(kq * 4) * OFFP * 8);
#pragma unroll
  for (int tap = 0; tap < 9; ++tap) {
    if (tap < 8) {
#pragma unroll
      for (int kq = 0; kq < 4; ++kq)
        Bf[tap + 1][kq] = *(const bf16x8*)(wbase +
            (size_t)((tap + 1) * 16 + kq * 4) * OFFP * 8);
    }
    const int dy = tap / 3, kxr = tap - dy * 3;
    const int s = lf + kxr;
#pragma unroll
    for (int kq = 0; kq < 4; ++kq) {
      const int ab = (((dy * 24 + s) * 128 + kq * 32 + q * 8) * 2) ^ ((s & 7) << 4);
      const bf16x8 a = *(const bf16x8*)((const char*)xr + ab);
      acc = __builtin_amdgcn_mfma_f32_16x16x32_bf16(a, Bf[tap][kq], acc, 0, 0, 0);
    }
  }
  const int co = nt * 16 + lf;
  const float bias = (co < 72) ? ob[co] : 0.f;
  float* orow = offb2 + ((size_t)n * HW + h * W_) * OFFP;
#pragma unroll
  for (int r = 0; r < 4; ++r) {
    const int w = w0 + q * 4 + r;
    if (w < W_) orow[(size_t)w * OFFP + co] = acc[r] + bias;
  }
}

// ---------------- deformable conv: setup -> pipelined sample+MFMA ----------------
// grid (196, 12), block 256, 4 waves = 4 groups. LDS 24.4 KB.
__global__ __launch_bounds__(256) void k_deform(const ushort* __restrict__ xcl,
    const float* __restrict__ offb2, const ushort* __restrict__ wd2,
    const float* __restrict__ cb, float* __restrict__ out) {
  __shared__ __align__(16) unsigned char sm[14208];
  __shared__ __align__(16) float outs[2560];   // [co][20] padded pixel stride
  ushort* swW = (ushort*)sm;            // [p*148 + (g*9+k)*4], 4736 B
  int* swO = (int*)(sm + 4736);         // [p*148 + (g*9+k)*4], 9472 B

  const int hw0 = blockIdx.x * 16;
  const int n = blockIdx.y;
  const int t = threadIdx.x;

  // ---- setup: one bilinear item per (p,g,k)
  for (int i = t; i < 576; i += 256) {
    const int p = i / 36;
    const int r = i - p * 36;
    const int g = r / 9;
    const int k = r - g * 9;
    const int hw = hw0 + p;
    const int h = hw / 56;
    const int w = hw - h * 56;
    const float2 o2 = *(const float2*)(offb2 + (size_t)(n * HW + hw) * OFFP + g * 18 + 2 * k);
    const int ky = k / 3 - 1;
    const int kx = k - (k / 3) * 3 - 1;
    const float py = (float)(h + ky) + o2.x;
    const float px = (float)(w + kx) + o2.y;
    const float y0f = floorf(py), x0f = floorf(px);
    const float ly = py - y0f, lx = px - x0f;
    const int y0 = (int)y0f, x0 = (int)x0f;
    const int y1 = y0 + 1, x1 = x0 + 1;
    const int yc0 = min(max(y0, 0), H_ - 1), yc1 = min(max(y1, 0), H_ - 1);
    const int xc0 = min(max(x0, 0), W_ - 1), xc1 = min(max(x1, 0), W_ - 1);
    const float my0 = ((unsigned)y0 < (unsigned)H_) ? 1.f : 0.f;
    const float my1 = ((unsigned)y1 < (unsigned)H_) ? 1.f : 0.f;
    const float mx0 = ((unsigned)x0 < (unsigned)W_) ? 1.f : 0.f;
    const float mx1 = ((unsigned)x1 < (unsigned)W_) ? 1.f : 0.f;
    ushort4 wq;
    wq.x = f2bf((1.f - ly) * (1.f - lx) * my0 * mx0);
    wq.y = f2bf((1.f - ly) * lx * my0 * mx1);
    wq.z = f2bf(ly * (1.f - lx) * my1 * mx0);
    wq.w = f2bf(ly * lx * my1 * mx1);
    *(ushort4*)(swW + p * 148 + (g * 9 + k) * 4) = wq;
    int4 oq;
    oq.x = (yc0 * 56 + xc0) * 128;
    oq.y = (yc0 * 56 + xc1) * 128;
    oq.z = (yc1 * 56 + xc0) * 128;
    oq.w = (yc1 * 56 + xc1) * 128;
    *(int4*)(swO + p * 148 + (g * 9 + k) * 4) = oq;
  }
  __syncthreads();

  // ---- pipelined sample+MFMA: wave = group g; lane (lf,q) samples its A-fragment
  const int l = t & 63;
  const int g = t >> 6;
  const int lf = l & 15, q = l >> 4;
  const ushort* xb = xcl + (size_t)n * HW * C_ + g * 32 + q * 8;
  const ushort* bb = wd2 + ((size_t)(g * 36 + q) * 32 + lf) * 8;
  const int sbase = lf * 148 + g * 36;
  f32x4 acc0 = {}, acc1 = {};

  ushort4 wq[9]; int4 oq[9];
  uint4 A00[9], A01[9], A10[9], A11[9];
  bf16x8 B0[9], B1[9];

#define LOADT(s_) do { \
    wq[s_] = *(const ushort4*)(swW + sbase + (s_) * 4); \
    oq[s_] = *(const int4*)(swO + sbase + (s_) * 4); } while (0)
#define GATHER(s_) do { \
    A00[s_] = *(const uint4*)(xb + oq[s_].x); \
    A01[s_] = *(const uint4*)(xb + oq[s_].y); \
    A10[s_] = *(const uint4*)(xb + oq[s_].z); \
    A11[s_] = *(const uint4*)(xb + oq[s_].w); } while (0)
#define LOADB(s_) do { \
    B0[s_] = *(const bf16x8*)(bb + (size_t)(s_) * 1024); \
    B1[s_] = *(const bf16x8*)(bb + (size_t)(s_) * 1024 + 128); } while (0)

  LOADT(0); LOADT(1);
  GATHER(0); LOADB(0);
#pragma unroll
  for (int ts = 0; ts < 9; ++ts) {
    if (ts < 7) LOADT(ts + 2);
    if (ts < 8) { GATHER(ts + 1); LOADB(ts + 1); }
    const float w00 = bf2f(wq[ts].x), w01 = bf2f(wq[ts].y);
    const float w10 = bf2f(wq[ts].z), w11 = bf2f(wq[ts].w);
    bf16x8 av;
#pragma unroll
    for (int j = 0; j < 4; ++j) {
      const unsigned int u00 = ((const unsigned int*)&A00[ts])[j];
      const unsigned int u01 = ((const unsigned int*)&A01[ts])[j];
      const unsigned int u10 = ((const unsigned int*)&A10[ts])[j];
      const unsigned int u11 = ((const unsigned int*)&A11[ts])[j];
      const float lo = fmaf(w00, __uint_as_float(u00 << 16),
                       fmaf(w01, __uint_as_float(u01 << 16),
                       fmaf(w10, __uint_as_float(u10 << 16),
                            w11 * __uint_as_float(u11 << 16))));
      const float hi = fmaf(w00, __uint_as_float(u00 & 0xFFFF0000u),
                       fmaf(w01, __uint_as_float(u01 & 0xFFFF0000u),
                       fmaf(w10, __uint_as_float(u10 & 0xFFFF0000u),
                            w11 * __uint_as_float(u11 & 0xFFFF0000u))));
      av[2 * j]     = (short)f2bf(lo);
      av[2 * j + 1] = (short)f2bf(hi);
    }
    acc0 = __builtin_amdgcn_mfma_f32_16x16x32_bf16(av, B0[ts], acc0, 0, 0, 0);
    acc1 = __builtin_amdgcn_mfma_f32_16x16x32_bf16(av, B1[ts], acc1, 0, 0, 0);
  }
#undef LOADT
#undef GATHER
#undef LOADB

#pragma unroll
  for (int r = 0; r < 4; ++r) {
    outs[(g * 32 + lf) * 20 + q * 4 + r] = acc0[r] + cb[g * 32 + lf];
    outs[(g * 32 + 16 + lf) * 20 + q * 4 + r] = acc1[r] + cb[g * 32 + 16 + lf];
  }
  __syncthreads();
  {
    const int co = t & 127;
    const int hf = t >> 7;
    const float4 v0 = *(const float4*)(outs + co * 20 + hf * 8);
    const float4 v1 = *(const float4*)(outs + co * 20 + hf * 8 + 4);
    const int b = n / D_, d = n - b * D_;
    float* dst = out + ((size_t)(b * COUT + co) * D_ + d) * HW + hw0 + hf * 8;
    *(float4*)dst = v0;
    *(float4*)(dst + 4) = v1;
  }
}

// ---------------- instance norm over (D,H,W) + exact GELU, in-place ----------------
__global__ __launch_bounds__(1024) void k_norm_gelu(float* __restrict__ io) {
  const int M = D_ * HW;       // 18816
  const int M4 = M / 4;        // 4704
  float4* p = (float4*)(io + (size_t)blockIdx.x * M);
  float s = 0.f, s2 = 0.f;
  for (int i = threadIdx.x; i < M4; i += 1024) {
    const float4 v = p[i];
    s += v.x + v.y + v.z + v.w;
    s2 = fmaf(v.x, v.x, fmaf(v.y, v.y, fmaf(v.z, v.z, fmaf(v.w, v.w, s2))));
  }
#pragma unroll
  for (int off = 32; off > 0; off >>= 1) {
    s += __shfl_down(s, off, 64);
    s2 += __shfl_down(s2, off, 64);
  }
  __shared__ float rs[16], rs2[16];
  __shared__ float smu, srstd;
  const int wid = threadIdx.x >> 6, lane = threadIdx.x & 63;
  if (lane == 0) { rs[wid] = s; rs2[wid] = s2; }
  __syncthreads();
  if (threadIdx.x == 0) {
    float ts = 0.f, t2 = 0.f;
#pragma unroll
    for (int i = 0; i < 16; ++i) { ts += rs[i]; t2 += rs2[i]; }
    const float mu = ts / (float)M;
    const float var = t2 / (float)M - mu * mu;
    smu = mu;
    srstd = rsqrtf(var + 1e-5f);
  }
  __syncthreads();
  const float mu = smu, rstd = srstd;
  for (int i = threadIdx.x; i < M4; i += 1024) {
    float4 v = p[i];
    v.x = (v.x - mu) * rstd; v.y = (v.y - mu) * rstd;
    v.z = (v.z - mu) * rstd; v.w = (v.w - mu) * rstd;
    v.x = 0.5f * v.x * (1.f + erff(v.x * 0.70710678118654752f));
    v.y = 0.5f * v.y * (1.f + erff(v.y * 0.70710678118654752f));
    v.z = 0.5f * v.z * (1.f + erff(v.z * 0.70710678118654752f));
    v.w = 0.5f * v.w * (1.f + erff(v.w * 0.70710678118654752f));
    p[i] = v;
  }
}

extern "C" void kernel_launch(void* const* d_in, const int* in_sizes, int n_in,
                              void* d_out, int out_size, void* d_ws, size_t ws_size,
                              hipStream_t stream) {
  const float* x  = (const float*)d_in[0];
  const float* ow = (const float*)d_in[1];
  const float* ob = (const float*)d_in[2];
  const float* cw = (const float*)d_in[3];
  const float* cb = (const float*)d_in[4];
  float* outp = (float*)d_out;

  char* wsb = (char*)d_ws;
  ushort* xcl   = (ushort*)wsb;                       // 9,633,792 B
  float*  offb2 = (float*)(wsb + 9633792);            // 12,042,240 B
  ushort* wd2   = (ushort*)(wsb + 21676032);          // 73,728 B
  ushort* wob2  = (ushort*)(wsb + 21749760);          // 184,320 B

  k_wprep<<<dim3(504), 256, 0, stream>>>(cw, ow, wd2, wob2);
  k_transpose<<<dim3(H_, 4, N_), 256, 0, stream>>>(x, xcl);
  k_offset_conv<<<dim3(4, H_, N_), 320, 0, stream>>>(xcl, wob2, ob, offb2);
  k_deform<<<dim3(196, N_), 256, 0, stream>>>(xcl, offb2, wd2, cb, outp);
  k_norm_gelu<<<dim3(B_ * COUT), 1024, 0, stream>>>(outp);
}

// Round 8
// 164.771 us; speedup vs baseline: 1.0429x; 1.0000x over previous
//
#include <hip/hip_runtime.h>
#include <hip/hip_bf16.h>

typedef __attribute__((ext_vector_type(8))) short bf16x8;
typedef __attribute__((ext_vector_type(4))) float f32x4;

#define B_   2
#define C_   128
#define D_   6
#define H_   56
#define W_   56
#define N_   12      // B_*D_
#define HW   3136
#define CSTR (D_*HW) // 18816
#define COUT 128
#define OFFP 80      // padded offset-channel stride (72 used)

__device__ __forceinline__ float bf2f(ushort u) {
  return __uint_as_float(((unsigned int)u) << 16);
}
__device__ __forceinline__ ushort f2bf(float f) {  // RNE
  unsigned int x = __float_as_uint(f);
  x += 0x7FFFu + ((x >> 16) & 1u);
  return (ushort)(x >> 16);
}

// ---------------- x (b,c,d,h,w) f32 -> xcl[n][hw][c] bf16 ----------------
__global__ __launch_bounds__(256) void k_transpose(const float* __restrict__ x,
                                                   ushort* __restrict__ xcl) {
  __shared__ float tile[32][57];
  const int h = blockIdx.x, c0 = blockIdx.y * 32, n = blockIdx.z;
  const int b = n / D_, d = n % D_;
  const float* src = x + (((size_t)(b * C_ + c0) * D_ + d) * HW) + h * W_;
  for (int i = threadIdx.x; i < 32 * W_; i += 256) {
    const int c = i / W_, w = i - c * W_;
    tile[c][w] = src[(size_t)c * CSTR + w];
  }
  __syncthreads();
  ushort* dst = xcl + ((size_t)(n * HW + h * W_)) * C_ + c0;
  for (int i = threadIdx.x; i < 32 * W_; i += 256) {
    const int w = i >> 5, c = i & 31;
    dst[(size_t)w * C_ + c] = f2bf(tile[c][w]);
  }
}

// ---- merged weight prep ----
// wd2[((g*36 + ts*4 + q)*32 + co_l)*8 + e] = cw[((g*32+co_l)*32 + q*8 + e)*9 + ts]
// wob2[((tap*16+kq*4+q)*80 + co)*8 + e]   = ow[(co*128 + kq*32+q*8+e)*9 + tap] (co<72)
__global__ void k_wprep(const float* __restrict__ cw, const float* __restrict__ ow,
                        ushort* __restrict__ wd2, ushort* __restrict__ wob2) {
  const int idx = blockIdx.x * 256 + threadIdx.x;  // < 129024
  if (idx < COUT * 288) {
    const int g = idx / 9216;
    const int r = idx - g * 9216;
    const int kb = r >> 8;           // 0..35
    const int co_l = (r >> 3) & 31;
    const int e = r & 7;
    const int ts = kb >> 2;
    const int q = kb & 3;
    wd2[idx] = f2bf(cw[((size_t)(g * 32 + co_l) * 32 + q * 8 + e) * 9 + ts]);
  } else if (idx < COUT * 288 + 144 * OFFP * 8) {
    const int i2 = idx - COUT * 288;
    const int e = i2 & 7;
    const int co = (i2 >> 3) % OFFP;
    const int kb = i2 / (OFFP * 8);   // 0..143
    const int tap = kb >> 4;
    const int r16 = kb & 15;
    const int kq = r16 >> 2;
    const int q = r16 & 3;
    const int c = kq * 32 + q * 8 + e;
    float v = 0.f;
    if (co < 72) v = ow[((size_t)co * C_ + c) * 9 + tap];
    wob2[i2] = f2bf(v);
  }
}

// ---------------- offset conv via MFMA implicit GEMM ----------------
// grid (4, 56, 12), block 320 = 5 waves; wave nt owns N-tile of 16 co; M-tile 16 px
__global__ __launch_bounds__(320) void k_offset_conv(const ushort* __restrict__ xcl,
    const ushort* __restrict__ wob2, const float* __restrict__ ob,
    float* __restrict__ offb2) {
  __shared__ __align__(16) ushort xr[3 * 24 * 128];  // 18432 B, XOR-swizzled
  const int w0 = blockIdx.x * 16;
  const int h = blockIdx.y, n = blockIdx.z;
  const int t = threadIdx.x;
  // stage rows h-1..h+1, slots s=0..17 (w = w0-1+s), zero-padded
  for (int i = t; i < 864; i += 320) {
    const int c16 = i & 15;
    const int sdy = i >> 4;          // 0..53
    const int s = sdy % 18;
    const int dy = sdy / 18;
    const int w = w0 - 1 + s;
    const int rr = h + dy - 1;
    const int c0 = c16 * 8;
    const int db = (((dy * 24 + s) * 128 + c0) * 2) ^ ((s & 7) << 4);
    uint4 v = {0u, 0u, 0u, 0u};
    if ((unsigned)rr < (unsigned)H_ && (unsigned)w < (unsigned)W_)
      v = *(const uint4*)(xcl + ((size_t)(n * HW + rr * W_ + w)) * C_ + c0);
    *(uint4*)((char*)xr + db) = v;
  }
  __syncthreads();
  const int l = t & 63;
  const int nt = t >> 6;             // 0..4
  const int lf = l & 15, q = l >> 4; // q 0..3
  const ushort* wbase = wob2 + ((size_t)q * OFFP + nt * 16 + lf) * 8;
  f32x4 acc = {};
  bf16x8 Bf[9][4];
#pragma unroll
  for (int kq = 0; kq < 4; ++kq)
    Bf[0][kq] = *(const bf16x8*)(wbase + (size_t)(kq * 4) * OFFP * 8);
#pragma unroll
  for (int tap = 0; tap < 9; ++tap) {
    if (tap < 8) {
#pragma unroll
      for (int kq = 0; kq < 4; ++kq)
        Bf[tap + 1][kq] = *(const bf16x8*)(wbase +
            (size_t)((tap + 1) * 16 + kq * 4) * OFFP * 8);
    }
    const int dy = tap / 3, kxr = tap - dy * 3;
    const int s = lf + kxr;
#pragma unroll
    for (int kq = 0; kq < 4; ++kq) {
      const int ab = (((dy * 24 + s) * 128 + kq * 32 + q * 8) * 2) ^ ((s & 7) << 4);
      const bf16x8 a = *(const bf16x8*)((const char*)xr + ab);
      acc = __builtin_amdgcn_mfma_f32_16x16x32_bf16(a, Bf[tap][kq], acc, 0, 0, 0);
    }
  }
  const int co = nt * 16 + lf;
  const float bias = (co < 72) ? ob[co] : 0.f;
  float* orow = offb2 + ((size_t)n * HW + h * W_) * OFFP;
#pragma unroll
  for (int r = 0; r < 4; ++r) {
    const int w = w0 + q * 4 + r;
    if (w < W_) orow[(size_t)w * OFFP + co] = acc[r] + bias;
  }
}

// ---------------- deformable conv: setup -> dual-tile pipelined sample+MFMA ----------------
// grid (98, 12), block 256, 4 waves = 4 groups; 32 px per block (2 tiles of 16 per wave).
// LDS: tables 28.4 KB, outs aliased after tables go dead.
__global__ __launch_bounds__(256) void k_deform(const ushort* __restrict__ xcl,
    const float* __restrict__ offb2, const ushort* __restrict__ wd2,
    const float* __restrict__ cb, float* __restrict__ out) {
  __shared__ __align__(16) unsigned char sm[28416];
  ushort* swW = (ushort*)sm;            // [p][37] x ushort4 : 32*37*8  = 9472 B
  int* swO = (int*)(sm + 9472);         // [p][37] x int4   : 32*37*16 = 18944 B
  float* outs = (float*)sm;             // [co][33] f32     : 16896 B (aliases tables)

  const int hw0 = blockIdx.x * 32;
  const int n = blockIdx.y;
  const int t = threadIdx.x;

  // ---- setup: one bilinear item per (p,g,k), p in 0..31
  for (int i = t; i < 1152; i += 256) {
    const int p = i / 36;
    const int r = i - p * 36;
    const int g = r / 9;
    const int k = r - g * 9;
    const int hw = hw0 + p;
    const int h = hw / 56;
    const int w = hw - h * 56;
    const float2 o2 = *(const float2*)(offb2 + (size_t)(n * HW + hw) * OFFP + g * 18 + 2 * k);
    const int ky = k / 3 - 1;
    const int kx = k - (k / 3) * 3 - 1;
    const float py = (float)(h + ky) + o2.x;
    const float px = (float)(w + kx) + o2.y;
    const float y0f = floorf(py), x0f = floorf(px);
    const float ly = py - y0f, lx = px - x0f;
    const int y0 = (int)y0f, x0 = (int)x0f;
    const int y1 = y0 + 1, x1 = x0 + 1;
    const int yc0 = min(max(y0, 0), H_ - 1), yc1 = min(max(y1, 0), H_ - 1);
    const int xc0 = min(max(x0, 0), W_ - 1), xc1 = min(max(x1, 0), W_ - 1);
    const float my0 = ((unsigned)y0 < (unsigned)H_) ? 1.f : 0.f;
    const float my1 = ((unsigned)y1 < (unsigned)H_) ? 1.f : 0.f;
    const float mx0 = ((unsigned)x0 < (unsigned)W_) ? 1.f : 0.f;
    const float mx1 = ((unsigned)x1 < (unsigned)W_) ? 1.f : 0.f;
    ushort4 wq;
    wq.x = f2bf((1.f - ly) * (1.f - lx) * my0 * mx0);
    wq.y = f2bf((1.f - ly) * lx * my0 * mx1);
    wq.z = f2bf(ly * (1.f - lx) * my1 * mx0);
    wq.w = f2bf(ly * lx * my1 * mx1);
    *(ushort4*)(swW + (p * 37 + g * 9 + k) * 4) = wq;
    int4 oq;
    oq.x = (yc0 * 56 + xc0) * 128;
    oq.y = (yc0 * 56 + xc1) * 128;
    oq.z = (yc1 * 56 + xc0) * 128;
    oq.w = (yc1 * 56 + xc1) * 128;
    *(int4*)(swO + (p * 37 + g * 9 + k) * 4) = oq;
  }
  __syncthreads();

  // ---- dual-tile pipelined sample+MFMA: wave = group g
  const int l = t & 63;
  const int g = t >> 6;
  const int lf = l & 15, q = l >> 4;
  const ushort* xb = xcl + (size_t)n * HW * C_ + g * 32 + q * 8;
  const ushort* bb = wd2 + ((size_t)(g * 36 + q) * 32 + lf) * 8;
  const int sb0 = (lf * 37 + g * 9) * 4;
  const int sb1 = ((lf + 16) * 37 + g * 9) * 4;
  f32x4 acc00 = {}, acc01 = {}, acc10 = {}, acc11 = {};

  ushort4 wq0[9], wq1[9]; int4 oq0[9], oq1[9];
  uint4 A0a[9], A0b[9], A0c[9], A0d[9];
  uint4 A1a[9], A1b[9], A1c[9], A1d[9];
  bf16x8 B0[9], B1[9];

#define PREF(s_) do { \
    wq0[s_] = *(const ushort4*)(swW + sb0 + (s_) * 4); \
    oq0[s_] = *(const int4*)(swO + sb0 + (s_) * 4); \
    wq1[s_] = *(const ushort4*)(swW + sb1 + (s_) * 4); \
    oq1[s_] = *(const int4*)(swO + sb1 + (s_) * 4); \
    A0a[s_] = *(const uint4*)(xb + oq0[s_].x); \
    A0b[s_] = *(const uint4*)(xb + oq0[s_].y); \
    A0c[s_] = *(const uint4*)(xb + oq0[s_].z); \
    A0d[s_] = *(const uint4*)(xb + oq0[s_].w); \
    A1a[s_] = *(const uint4*)(xb + oq1[s_].x); \
    A1b[s_] = *(const uint4*)(xb + oq1[s_].y); \
    A1c[s_] = *(const uint4*)(xb + oq1[s_].z); \
    A1d[s_] = *(const uint4*)(xb + oq1[s_].w); \
    B0[s_] = *(const bf16x8*)(bb + (size_t)(s_) * 1024); \
    B1[s_] = *(const bf16x8*)(bb + (size_t)(s_) * 1024 + 128); } while (0)

#define LERP(av_, wqv_, Aa_, Ab_, Ac_, Ad_) do { \
    const float w00 = bf2f(wqv_.x), w01 = bf2f(wqv_.y); \
    const float w10 = bf2f(wqv_.z), w11 = bf2f(wqv_.w); \
    _Pragma("unroll") \
    for (int j = 0; j < 4; ++j) { \
      const unsigned int u00 = ((const unsigned int*)&Aa_)[j]; \
      const unsigned int u01 = ((const unsigned int*)&Ab_)[j]; \
      const unsigned int u10 = ((const unsigned int*)&Ac_)[j]; \
      const unsigned int u11 = ((const unsigned int*)&Ad_)[j]; \
      const float lo = fmaf(w00, __uint_as_float(u00 << 16), \
                       fmaf(w01, __uint_as_float(u01 << 16), \
                       fmaf(w10, __uint_as_float(u10 << 16), \
                            w11 * __uint_as_float(u11 << 16)))); \
      const float hi = fmaf(w00, __uint_as_float(u00 & 0xFFFF0000u), \
                       fmaf(w01, __uint_as_float(u01 & 0xFFFF0000u), \
                       fmaf(w10, __uint_as_float(u10 & 0xFFFF0000u), \
                            w11 * __uint_as_float(u11 & 0xFFFF0000u)))); \
      av_[2 * j]     = (short)f2bf(lo); \
      av_[2 * j + 1] = (short)f2bf(hi); \
    } } while (0)

  PREF(0);
#pragma unroll
  for (int ts = 0; ts < 9; ++ts) {
    if (ts < 8) PREF(ts + 1);
    __builtin_amdgcn_sched_barrier(0);
    {
      bf16x8 av0, av1;
      LERP(av0, wq0[ts], A0a[ts], A0b[ts], A0c[ts], A0d[ts]);
      acc00 = __builtin_amdgcn_mfma_f32_16x16x32_bf16(av0, B0[ts], acc00, 0, 0, 0);
      acc01 = __builtin_amdgcn_mfma_f32_16x16x32_bf16(av0, B1[ts], acc01, 0, 0, 0);
      LERP(av1, wq1[ts], A1a[ts], A1b[ts], A1c[ts], A1d[ts]);
      acc10 = __builtin_amdgcn_mfma_f32_16x16x32_bf16(av1, B0[ts], acc10, 0, 0, 0);
      acc11 = __builtin_amdgcn_mfma_f32_16x16x32_bf16(av1, B1[ts], acc11, 0, 0, 0);
    }
  }
#undef PREF
#undef LERP

  __syncthreads();   // all waves done reading tables; outs may alias
  {
    const float b0 = cb[g * 32 + lf];
    const float b1 = cb[g * 32 + 16 + lf];
#pragma unroll
    for (int r = 0; r < 4; ++r) {
      outs[(g * 32 + lf) * 33 + q * 4 + r]       = acc00[r] + b0;
      outs[(g * 32 + 16 + lf) * 33 + q * 4 + r]  = acc01[r] + b1;
      outs[(g * 32 + lf) * 33 + 16 + q * 4 + r]      = acc10[r] + b0;
      outs[(g * 32 + 16 + lf) * 33 + 16 + q * 4 + r] = acc11[r] + b1;
    }
  }
  __syncthreads();
  {
    const int co = t & 127;
    const int hf = t >> 7;           // 0..1, 16 px each
    const float* srcp = outs + co * 33 + hf * 16;
    const int b = n / D_, d = n - b * D_;
    float* dst = out + ((size_t)(b * COUT + co) * D_ + d) * HW + hw0 + hf * 16;
#pragma unroll
    for (int v4 = 0; v4 < 4; ++v4)
      *(float4*)(dst + v4 * 4) = *(const float4*)(srcp + v4 * 4);
  }
}

// ---------------- instance norm over (D,H,W) + exact GELU, in-place ----------------
__global__ __launch_bounds__(1024) void k_norm_gelu(float* __restrict__ io) {
  const int M = D_ * HW;       // 18816
  const int M4 = M / 4;        // 4704
  float4* p = (float4*)(io + (size_t)blockIdx.x * M);
  float s = 0.f, s2 = 0.f;
  for (int i = threadIdx.x; i < M4; i += 1024) {
    const float4 v = p[i];
    s += v.x + v.y + v.z + v.w;
    s2 = fmaf(v.x, v.x, fmaf(v.y, v.y, fmaf(v.z, v.z, fmaf(v.w, v.w, s2))));
  }
#pragma unroll
  for (int off = 32; off > 0; off >>= 1) {
    s += __shfl_down(s, off, 64);
    s2 += __shfl_down(s2, off, 64);
  }
  __shared__ float rs[16], rs2[16];
  __shared__ float smu, srstd;
  const int wid = threadIdx.x >> 6, lane = threadIdx.x & 63;
  if (lane == 0) { rs[wid] = s; rs2[wid] = s2; }
  __syncthreads();
  if (threadIdx.x == 0) {
    float ts = 0.f, t2 = 0.f;
#pragma unroll
    for (int i = 0; i < 16; ++i) { ts += rs[i]; t2 += rs2[i]; }
    const float mu = ts / (float)M;
    const float var = t2 / (float)M - mu * mu;
    smu = mu;
    srstd = rsqrtf(var + 1e-5f);
  }
  __syncthreads();
  const float mu = smu, rstd = srstd;
  for (int i = threadIdx.x; i < M4; i += 1024) {
    float4 v = p[i];
    v.x = (v.x - mu) * rstd; v.y = (v.y - mu) * rstd;
    v.z = (v.z - mu) * rstd; v.w = (v.w - mu) * rstd;
    v.x = 0.5f * v.x * (1.f + erff(v.x * 0.70710678118654752f));
    v.y = 0.5f * v.y * (1.f + erff(v.y * 0.70710678118654752f));
    v.z = 0.5f * v.z * (1.f + erff(v.z * 0.70710678118654752f));
    v.w = 0.5f * v.w * (1.f + erff(v.w * 0.70710678118654752f));
    p[i] = v;
  }
}

extern "C" void kernel_launch(void* const* d_in, const int* in_sizes, int n_in,
                              void* d_out, int out_size, void* d_ws, size_t ws_size,
                              hipStream_t stream) {
  const float* x  = (const float*)d_in[0];
  const float* ow = (const float*)d_in[1];
  const float* ob = (const float*)d_in[2];
  const float* cw = (const float*)d_in[3];
  const float* cb = (const float*)d_in[4];
  float* outp = (float*)d_out;

  char* wsb = (char*)d_ws;
  ushort* xcl   = (ushort*)wsb;                       // 9,633,792 B
  float*  offb2 = (float*)(wsb + 9633792);            // 12,042,240 B
  ushort* wd2   = (ushort*)(wsb + 21676032);          // 73,728 B
  ushort* wob2  = (ushort*)(wsb + 21749760);          // 184,320 B

  k_wprep<<<dim3(504), 256, 0, stream>>>(cw, ow, wd2, wob2);
  k_transpose<<<dim3(H_, 4, N_), 256, 0, stream>>>(x, xcl);
  k_offset_conv<<<dim3(4, H_, N_), 320, 0, stream>>>(xcl, wob2, ob, offb2);
  k_deform<<<dim3(98, N_), 256, 0, stream>>>(xcl, offb2, wd2, cb, outp);
  k_norm_gelu<<<dim3(B_ * COUT), 1024, 0, stream>>>(outp);
}

// Round 9
// 160.478 us; speedup vs baseline: 1.0708x; 1.0268x over previous
//
#include <hip/hip_runtime.h>
#include <hip/hip_bf16.h>

typedef __attribute__((ext_vector_type(8))) short bf16x8;
typedef __attribute__((ext_vector_type(4))) float f32x4;

#define B_   2
#define C_   128
#define D_   6
#define H_   56
#define W_   56
#define N_   12      // B_*D_
#define HW   3136
#define CSTR (D_*HW) // 18816
#define COUT 128
#define OFFP 80      // padded offset-channel stride (72 used)

__device__ __forceinline__ float bf2f(ushort u) {
  return __uint_as_float(((unsigned int)u) << 16);
}
__device__ __forceinline__ ushort f2bf(float f) {  // RNE
  unsigned int x = __float_as_uint(f);
  x += 0x7FFFu + ((x >> 16) & 1u);
  return (ushort)(x >> 16);
}

// ---------------- x (b,c,d,h,w) f32 -> xcl[n][hw][c] bf16 ----------------
__global__ __launch_bounds__(256) void k_transpose(const float* __restrict__ x,
                                                   ushort* __restrict__ xcl) {
  __shared__ float tile[32][57];
  const int h = blockIdx.x, c0 = blockIdx.y * 32, n = blockIdx.z;
  const int b = n / D_, d = n % D_;
  const float* src = x + (((size_t)(b * C_ + c0) * D_ + d) * HW) + h * W_;
  for (int i = threadIdx.x; i < 32 * W_; i += 256) {
    const int c = i / W_, w = i - c * W_;
    tile[c][w] = src[(size_t)c * CSTR + w];
  }
  __syncthreads();
  ushort* dst = xcl + ((size_t)(n * HW + h * W_)) * C_ + c0;
  for (int i = threadIdx.x; i < 32 * W_; i += 256) {
    const int w = i >> 5, c = i & 31;
    dst[(size_t)w * C_ + c] = f2bf(tile[c][w]);
  }
}

// ---- merged weight prep ----
// wd2[((g*36 + ts*4 + q)*32 + co_l)*8 + e] = cw[((g*32+co_l)*32 + q*8 + e)*9 + ts]
// wob2[((tap*16+kq*4+q)*80 + co)*8 + e]   = ow[(co*128 + kq*32+q*8+e)*9 + tap] (co<72)
__global__ void k_wprep(const float* __restrict__ cw, const float* __restrict__ ow,
                        ushort* __restrict__ wd2, ushort* __restrict__ wob2) {
  const int idx = blockIdx.x * 256 + threadIdx.x;  // < 129024
  if (idx < COUT * 288) {
    const int g = idx / 9216;
    const int r = idx - g * 9216;
    const int kb = r >> 8;           // 0..35
    const int co_l = (r >> 3) & 31;
    const int e = r & 7;
    const int ts = kb >> 2;
    const int q = kb & 3;
    wd2[idx] = f2bf(cw[((size_t)(g * 32 + co_l) * 32 + q * 8 + e) * 9 + ts]);
  } else if (idx < COUT * 288 + 144 * OFFP * 8) {
    const int i2 = idx - COUT * 288;
    const int e = i2 & 7;
    const int co = (i2 >> 3) % OFFP;
    const int kb = i2 / (OFFP * 8);   // 0..143
    const int tap = kb >> 4;
    const int r16 = kb & 15;
    const int kq = r16 >> 2;
    const int q = r16 & 3;
    const int c = kq * 32 + q * 8 + e;
    float v = 0.f;
    if (co < 72) v = ow[((size_t)co * C_ + c) * 9 + tap];
    wob2[i2] = f2bf(v);
  }
}

// ---------------- offset conv via MFMA implicit GEMM ----------------
// grid (4, 56, 12), block 320 = 5 waves; wave nt owns N-tile of 16 co; M-tile 16 px
__global__ __launch_bounds__(320) void k_offset_conv(const ushort* __restrict__ xcl,
    const ushort* __restrict__ wob2, const float* __restrict__ ob,
    float* __restrict__ offb2) {
  __shared__ __align__(16) ushort xr[3 * 24 * 128];  // 18432 B, XOR-swizzled
  const int w0 = blockIdx.x * 16;
  const int h = blockIdx.y, n = blockIdx.z;
  const int t = threadIdx.x;
  // stage rows h-1..h+1, slots s=0..17 (w = w0-1+s), zero-padded
  for (int i = t; i < 864; i += 320) {
    const int c16 = i & 15;
    const int sdy = i >> 4;          // 0..53
    const int s = sdy % 18;
    const int dy = sdy / 18;
    const int w = w0 - 1 + s;
    const int rr = h + dy - 1;
    const int c0 = c16 * 8;
    const int db = (((dy * 24 + s) * 128 + c0) * 2) ^ ((s & 7) << 4);
    uint4 v = {0u, 0u, 0u, 0u};
    if ((unsigned)rr < (unsigned)H_ && (unsigned)w < (unsigned)W_)
      v = *(const uint4*)(xcl + ((size_t)(n * HW + rr * W_ + w)) * C_ + c0);
    *(uint4*)((char*)xr + db) = v;
  }
  __syncthreads();
  const int l = t & 63;
  const int nt = t >> 6;             // 0..4
  const int lf = l & 15, q = l >> 4; // q 0..3
  const ushort* wbase = wob2 + ((size_t)q * OFFP + nt * 16 + lf) * 8;
  f32x4 acc = {};
  bf16x8 Bf[9][4];
#pragma unroll
  for (int kq = 0; kq < 4; ++kq)
    Bf[0][kq] = *(const bf16x8*)(wbase + (size_t)(kq * 4) * OFFP * 8);
#pragma unroll
  for (int tap = 0; tap < 9; ++tap) {
    if (tap < 8) {
#pragma unroll
      for (int kq = 0; kq < 4; ++kq)
        Bf[tap + 1][kq] = *(const bf16x8*)(wbase +
            (size_t)((tap + 1) * 16 + kq * 4) * OFFP * 8);
    }
    const int dy = tap / 3, kxr = tap - dy * 3;
    const int s = lf + kxr;
#pragma unroll
    for (int kq = 0; kq < 4; ++kq) {
      const int ab = (((dy * 24 + s) * 128 + kq * 32 + q * 8) * 2) ^ ((s & 7) << 4);
      const bf16x8 a = *(const bf16x8*)((const char*)xr + ab);
      acc = __builtin_amdgcn_mfma_f32_16x16x32_bf16(a, Bf[tap][kq], acc, 0, 0, 0);
    }
  }
  const int co = nt * 16 + lf;
  const float bias = (co < 72) ? ob[co] : 0.f;
  float* orow = offb2 + ((size_t)n * HW + h * W_) * OFFP;
#pragma unroll
  for (int r = 0; r < 4; ++r) {
    const int w = w0 + q * 4 + r;
    if (w < W_) orow[(size_t)w * OFFP + co] = acc[r] + bias;
  }
}

// ---------------- sampler: gather+lerp -> smp[n][g][tap][hw][32c] bf16 ----------------
// grid (196, 12), block 256 = 4 waves (wave = g); lane = px*4 + c8. 16 px per block.
__global__ __launch_bounds__(256) void k_sample(const ushort* __restrict__ xcl,
    const float* __restrict__ offb2, ushort* __restrict__ smp) {
  __shared__ __align__(16) ushort swW[16 * 37 * 4];  // 4736 B
  __shared__ __align__(16) int swO[16 * 37 * 4];     // 9472 B
  const int hw0 = blockIdx.x * 16;
  const int n = blockIdx.y;
  const int t = threadIdx.x;

  // ---- setup: one bilinear item per (p,g,k), p in 0..15
  for (int i = t; i < 576; i += 256) {
    const int p = i / 36;
    const int r = i - p * 36;
    const int g = r / 9;
    const int k = r - g * 9;
    const int hw = hw0 + p;
    const int h = hw / 56;
    const int w = hw - h * 56;
    const float2 o2 = *(const float2*)(offb2 + (size_t)(n * HW + hw) * OFFP + g * 18 + 2 * k);
    const int ky = k / 3 - 1;
    const int kx = k - (k / 3) * 3 - 1;
    const float py = (float)(h + ky) + o2.x;
    const float px = (float)(w + kx) + o2.y;
    const float y0f = floorf(py), x0f = floorf(px);
    const float ly = py - y0f, lx = px - x0f;
    const int y0 = (int)y0f, x0 = (int)x0f;
    const int y1 = y0 + 1, x1 = x0 + 1;
    const int yc0 = min(max(y0, 0), H_ - 1), yc1 = min(max(y1, 0), H_ - 1);
    const int xc0 = min(max(x0, 0), W_ - 1), xc1 = min(max(x1, 0), W_ - 1);
    const float my0 = ((unsigned)y0 < (unsigned)H_) ? 1.f : 0.f;
    const float my1 = ((unsigned)y1 < (unsigned)H_) ? 1.f : 0.f;
    const float mx0 = ((unsigned)x0 < (unsigned)W_) ? 1.f : 0.f;
    const float mx1 = ((unsigned)x1 < (unsigned)W_) ? 1.f : 0.f;
    ushort4 wq;
    wq.x = f2bf((1.f - ly) * (1.f - lx) * my0 * mx0);
    wq.y = f2bf((1.f - ly) * lx * my0 * mx1);
    wq.z = f2bf(ly * (1.f - lx) * my1 * mx0);
    wq.w = f2bf(ly * lx * my1 * mx1);
    *(ushort4*)(swW + (p * 37 + g * 9 + k) * 4) = wq;
    int4 oq;
    oq.x = (yc0 * 56 + xc0) * 128;
    oq.y = (yc0 * 56 + xc1) * 128;
    oq.z = (yc1 * 56 + xc0) * 128;
    oq.w = (yc1 * 56 + xc1) * 128;
    *(int4*)(swO + (p * 37 + g * 9 + k) * 4) = oq;
  }
  __syncthreads();

  // ---- gather+lerp: thread = (g, px, c8); 9 independent taps
  const int g = t >> 6;
  const int px = (t >> 2) & 15;
  const int c8 = t & 3;
  const ushort* xb = xcl + (size_t)n * HW * C_ + g * 32 + c8 * 8;
  ushort* sd = smp + (((size_t)(n * 4 + g) * 9) * HW + hw0 + px) * 32 + c8 * 8;
  const int tb = (px * 37 + g * 9) * 4;
#pragma unroll 3
  for (int k = 0; k < 9; ++k) {
    const ushort4 wq = *(const ushort4*)(swW + tb + k * 4);
    const int4 oq = *(const int4*)(swO + tb + k * 4);
    const uint4 c00 = *(const uint4*)(xb + oq.x);
    const uint4 c01 = *(const uint4*)(xb + oq.y);
    const uint4 c10 = *(const uint4*)(xb + oq.z);
    const uint4 c11 = *(const uint4*)(xb + oq.w);
    const float w00 = bf2f(wq.x), w01 = bf2f(wq.y);
    const float w10 = bf2f(wq.z), w11 = bf2f(wq.w);
    bf16x8 av;
#pragma unroll
    for (int j = 0; j < 4; ++j) {
      const unsigned int u00 = ((const unsigned int*)&c00)[j];
      const unsigned int u01 = ((const unsigned int*)&c01)[j];
      const unsigned int u10 = ((const unsigned int*)&c10)[j];
      const unsigned int u11 = ((const unsigned int*)&c11)[j];
      const float lo = fmaf(w00, __uint_as_float(u00 << 16),
                       fmaf(w01, __uint_as_float(u01 << 16),
                       fmaf(w10, __uint_as_float(u10 << 16),
                            w11 * __uint_as_float(u11 << 16))));
      const float hi = fmaf(w00, __uint_as_float(u00 & 0xFFFF0000u),
                       fmaf(w01, __uint_as_float(u01 & 0xFFFF0000u),
                       fmaf(w10, __uint_as_float(u10 & 0xFFFF0000u),
                            w11 * __uint_as_float(u11 & 0xFFFF0000u))));
      av[2 * j]     = (short)f2bf(lo);
      av[2 * j + 1] = (short)f2bf(hi);
    }
    *(bf16x8*)(sd + (size_t)k * (HW * 32)) = av;
  }
}

// ---------------- dense grouped GEMM: out = smp x wd2 ----------------
// grid (98, 12), block 256 = 4 waves (wave = g); 32 px x 128 co per block.
__global__ __launch_bounds__(256) void k_dgemm(const ushort* __restrict__ smp,
    const ushort* __restrict__ wd2, const float* __restrict__ cb,
    float* __restrict__ out) {
  const int hw0 = blockIdx.x * 32;
  const int n = blockIdx.y;
  const int t = threadIdx.x;
  const int l = t & 63;
  const int g = t >> 6;
  const int lf = l & 15, q = l >> 4;
  const ushort* abase = smp + (((size_t)(n * 4 + g) * 9) * HW + hw0 + lf) * 32 + q * 8;
  const ushort* bb = wd2 + ((size_t)(g * 36 + q) * 32 + lf) * 8;
  f32x4 acc00 = {}, acc01 = {}, acc10 = {}, acc11 = {};
#pragma unroll 3
  for (int ts = 0; ts < 9; ++ts) {
    const bf16x8 a0 = *(const bf16x8*)(abase + (size_t)ts * (HW * 32));
    const bf16x8 a1 = *(const bf16x8*)(abase + (size_t)ts * (HW * 32) + 16 * 32);
    const bf16x8 b0 = *(const bf16x8*)(bb + (size_t)ts * 1024);
    const bf16x8 b1 = *(const bf16x8*)(bb + (size_t)ts * 1024 + 128);
    acc00 = __builtin_amdgcn_mfma_f32_16x16x32_bf16(a0, b0, acc00, 0, 0, 0);
    acc01 = __builtin_amdgcn_mfma_f32_16x16x32_bf16(a0, b1, acc01, 0, 0, 0);
    acc10 = __builtin_amdgcn_mfma_f32_16x16x32_bf16(a1, b0, acc10, 0, 0, 0);
    acc11 = __builtin_amdgcn_mfma_f32_16x16x32_bf16(a1, b1, acc11, 0, 0, 0);
  }
  const int b = n / D_, d = n - b * D_;
  const float bias0 = cb[g * 32 + lf];
  const float bias1 = cb[g * 32 + 16 + lf];
  float* d00 = out + ((size_t)(b * COUT + g * 32 + lf) * D_ + d) * HW + hw0 + q * 4;
  float* d01 = out + ((size_t)(b * COUT + g * 32 + 16 + lf) * D_ + d) * HW + hw0 + q * 4;
  float4 v;
  v.x = acc00[0] + bias0; v.y = acc00[1] + bias0; v.z = acc00[2] + bias0; v.w = acc00[3] + bias0;
  *(float4*)d00 = v;
  v.x = acc01[0] + bias1; v.y = acc01[1] + bias1; v.z = acc01[2] + bias1; v.w = acc01[3] + bias1;
  *(float4*)d01 = v;
  v.x = acc10[0] + bias0; v.y = acc10[1] + bias0; v.z = acc10[2] + bias0; v.w = acc10[3] + bias0;
  *(float4*)(d00 + 16) = v;
  v.x = acc11[0] + bias1; v.y = acc11[1] + bias1; v.z = acc11[2] + bias1; v.w = acc11[3] + bias1;
  *(float4*)(d01 + 16) = v;
}

// ---------------- instance norm over (D,H,W) + exact GELU, in-place ----------------
__global__ __launch_bounds__(1024) void k_norm_gelu(float* __restrict__ io) {
  const int M = D_ * HW;       // 18816
  const int M4 = M / 4;        // 4704
  float4* p = (float4*)(io + (size_t)blockIdx.x * M);
  float s = 0.f, s2 = 0.f;
  for (int i = threadIdx.x; i < M4; i += 1024) {
    const float4 v = p[i];
    s += v.x + v.y + v.z + v.w;
    s2 = fmaf(v.x, v.x, fmaf(v.y, v.y, fmaf(v.z, v.z, fmaf(v.w, v.w, s2))));
  }
#pragma unroll
  for (int off = 32; off > 0; off >>= 1) {
    s += __shfl_down(s, off, 64);
    s2 += __shfl_down(s2, off, 64);
  }
  __shared__ float rs[16], rs2[16];
  __shared__ float smu, srstd;
  const int wid = threadIdx.x >> 6, lane = threadIdx.x & 63;
  if (lane == 0) { rs[wid] = s; rs2[wid] = s2; }
  __syncthreads();
  if (threadIdx.x == 0) {
    float ts = 0.f, t2 = 0.f;
#pragma unroll
    for (int i = 0; i < 16; ++i) { ts += rs[i]; t2 += rs2[i]; }
    const float mu = ts / (float)M;
    const float var = t2 / (float)M - mu * mu;
    smu = mu;
    srstd = rsqrtf(var + 1e-5f);
  }
  __syncthreads();
  const float mu = smu, rstd = srstd;
  for (int i = threadIdx.x; i < M4; i += 1024) {
    float4 v = p[i];
    v.x = (v.x - mu) * rstd; v.y = (v.y - mu) * rstd;
    v.z = (v.z - mu) * rstd; v.w = (v.w - mu) * rstd;
    v.x = 0.5f * v.x * (1.f + erff(v.x * 0.70710678118654752f));
    v.y = 0.5f * v.y * (1.f + erff(v.y * 0.70710678118654752f));
    v.z = 0.5f * v.z * (1.f + erff(v.z * 0.70710678118654752f));
    v.w = 0.5f * v.w * (1.f + erff(v.w * 0.70710678118654752f));
    p[i] = v;
  }
}

extern "C" void kernel_launch(void* const* d_in, const int* in_sizes, int n_in,
                              void* d_out, int out_size, void* d_ws, size_t ws_size,
                              hipStream_t stream) {
  const float* x  = (const float*)d_in[0];
  const float* ow = (const float*)d_in[1];
  const float* ob = (const float*)d_in[2];
  const float* cw = (const float*)d_in[3];
  const float* cb = (const float*)d_in[4];
  float* outp = (float*)d_out;

  char* wsb = (char*)d_ws;
  ushort* xcl   = (ushort*)wsb;                       // 9,633,792 B
  float*  offb2 = (float*)(wsb + 9633792);            // 12,042,240 B
  ushort* wd2   = (ushort*)(wsb + 21676032);          // 73,728 B
  ushort* wob2  = (ushort*)(wsb + 21749760);          // 184,320 B
  ushort* smp   = (ushort*)(wsb + 21934080);          // 21,676,032 B (total ~43.6 MB)

  k_wprep<<<dim3(504), 256, 0, stream>>>(cw, ow, wd2, wob2);
  k_transpose<<<dim3(H_, 4, N_), 256, 0, stream>>>(x, xcl);
  k_offset_conv<<<dim3(4, H_, N_), 320, 0, stream>>>(xcl, wob2, ob, offb2);
  k_sample<<<dim3(196, N_), 256, 0, stream>>>(xcl, offb2, smp);
  k_dgemm<<<dim3(98, N_), 256, 0, stream>>>(smp, wd2, cb, outp);
  k_norm_gelu<<<dim3(B_ * COUT), 1024, 0, stream>>>(outp);
}